// Round 6
// baseline (315.059 us; speedup 1.0000x reference)
//
#include <hip/hip_runtime.h>
#include <hip/hip_bf16.h>
#include <stddef.h>

typedef __attribute__((ext_vector_type(8))) short short8;
typedef __attribute__((ext_vector_type(4))) short short4v;
typedef __attribute__((ext_vector_type(4))) unsigned short ushort4v;
typedef __attribute__((ext_vector_type(4))) float floatx4;

#define N_ 4
#define C_ 256
#define H_ 128
#define W_ 128
#define HW_ (H_*W_)
#define NPX_ (N_*HW_)   // 65536
#define CD_ 64     // C/4
#define E_ 36      // k2*up2
#define OC_ 256

// round-to-nearest-even f32 -> bf16 bits
static __device__ __forceinline__ unsigned short f2bf(float f) {
    union { float f; unsigned u; } v; v.f = f;
    unsigned r = v.u + 0x7fff + ((v.u >> 16) & 1);
    return (unsigned short)(r >> 16);
}
static __device__ __forceinline__ float bf2f(unsigned short s) {
    union { unsigned u; float f; } v; v.u = ((unsigned)s) << 16;
    return v.f;
}

// ---------------- Kernel 0: w_out -> bf16 ; w_enc -> weT[e][tap][c] ----------------
__global__ __launch_bounds__(256) void k_prep(const float* __restrict__ wo,
                                              short* __restrict__ wob,
                                              const float* __restrict__ we,
                                              float* __restrict__ weT) {
    int bx = blockIdx.x;
    if (bx < 64) {
        int i = (bx * 256 + threadIdx.x) * 4;
        float4 v = *(const float4*)&wo[i];
        short4v s;
        s.x = (short)f2bf(v.x); s.y = (short)f2bf(v.y);
        s.z = (short)f2bf(v.z); s.w = (short)f2bf(v.w);
        *(short4v*)&wob[i] = s;
    } else {
        int idx = (bx - 64) * 256 + threadIdx.x;   // < 36*9*64 = 20736
        if (idx < E_ * 9 * 64) {
            int c = idx & 63;
            int r = idx >> 6;          // e*9 + tap
            int tap = r % 9, e = r / 9;
            weT[idx] = we[((size_t)e * 64 + c) * 9 + tap];
        }
    }
}

// ---------------- Kernel 1: 1x1 down conv as f32 GEMM, channel-last out ----------------
// grid 512 = n(4) * pxchunk(128 of 128px); 512 thr; tile M=64 x N=128, K=256/32
// t layout: [n*HW + px][64]  (channel-last)
#define WST 68
#define XST 132
__global__ __launch_bounds__(512) void k_down(
    const float* __restrict__ x, const float* __restrict__ wd,
    const float* __restrict__ bd, float* __restrict__ t)
{
    __shared__ float Wsm[32 * WST];   // [k][o]  8.7 KB
    __shared__ float Xs[32 * XST];    // [k][px] 16.9 KB
    int tid = threadIdx.x;
    int bx = blockIdx.x;
    int n = bx >> 7;
    int px0 = (bx & 127) * 128;
    int mg = tid & 15;               // o-quad: o = mg*4  (fast-varying for coalesced store)
    int ng = tid >> 4;               // px group of 4
    float acc[4][4];
    #pragma unroll
    for (int i = 0; i < 4; i++)
        #pragma unroll
        for (int j = 0; j < 4; j++) acc[i][j] = 0.f;

    for (int c0 = 0; c0 < C_; c0 += 32) {
        {
            int o = tid >> 3, kb = tid & 7;
            float4 wv = *(const float4*)&wd[o * C_ + c0 + kb * 4];
            Wsm[(kb * 4 + 0) * WST + o] = wv.x;
            Wsm[(kb * 4 + 1) * WST + o] = wv.y;
            Wsm[(kb * 4 + 2) * WST + o] = wv.z;
            Wsm[(kb * 4 + 3) * WST + o] = wv.w;
        }
        {
            int c = tid >> 4, pg = tid & 15;
            const float* xp = &x[((size_t)n * C_ + c0 + c) * HW_ + px0 + pg * 8];
            #pragma unroll
            for (int i = 0; i < 2; i++) {
                float4 v = *(const float4*)(xp + i * 4);
                *(float4*)&Xs[c * XST + pg * 8 + i * 4] = v;
            }
        }
        __syncthreads();
        #pragma unroll 4
        for (int k = 0; k < 32; k++) {
            float4 wv = *(const float4*)&Wsm[k * WST + mg * 4];
            float4 xv = *(const float4*)&Xs[k * XST + ng * 4];
            float xs[4] = {xv.x, xv.y, xv.z, xv.w};
            float ws[4] = {wv.x, wv.y, wv.z, wv.w};
            #pragma unroll
            for (int i = 0; i < 4; i++)
                #pragma unroll
                for (int j = 0; j < 4; j++)
                    acc[i][j] = fmaf(ws[i], xs[j], acc[i][j]);
        }
        __syncthreads();
    }
    float b0 = bd[mg * 4 + 0], b1 = bd[mg * 4 + 1], b2 = bd[mg * 4 + 2], b3 = bd[mg * 4 + 3];
    #pragma unroll
    for (int j = 0; j < 4; j++) {
        float4 r;
        r.x = acc[0][j] + b0; r.y = acc[1][j] + b1;
        r.z = acc[2][j] + b2; r.w = acc[3][j] + b3;
        *(float4*)&t[((size_t)n * HW_ + px0 + ng * 4 + j) * 64 + mg * 4] = r;
    }
}

// ---------------- Kernel 2: 3x3 enc conv + softmax (channel-last t, plane kern) ----------------
// grid 1024 = q(4) * pxblk(256); 256 thr, 1 px/thread, 9 k's per thread.
// kern layout: [36][NPX] planes -> dense coalesced writes.
__global__ __launch_bounds__(256) void k_enc(
    const float* __restrict__ t, const float* __restrict__ weT,
    const float* __restrict__ be, float* __restrict__ kern)
{
    int q = blockIdx.x >> 8;
    int px = (blockIdx.x & 255) * 256 + threadIdx.x;   // 0..65535
    int n = px >> 14;
    int hw = px & (HW_ - 1);
    int h = hw >> 7, w = hw & (W_ - 1);
    float acc[9];
    #pragma unroll
    for (int k = 0; k < 9; k++) acc[k] = be[k * 4 + q];

    #pragma unroll
    for (int di = 0; di < 3; di++) {
        int hh = h + di - 1;
        #pragma unroll
        for (int dj = 0; dj < 3; dj++) {
            int ww = w + dj - 1;
            if (hh >= 0 && hh < H_ && ww >= 0 && ww < W_) {
                int tap = di * 3 + dj;
                const float* tp = t + ((size_t)n * HW_ + hh * W_ + ww) * 64;
                #pragma unroll 4
                for (int cq = 0; cq < 16; cq++) {
                    float4 tv = *(const float4*)(tp + cq * 4);
                    #pragma unroll
                    for (int k = 0; k < 9; k++) {
                        const float* wp = weT + (size_t)(36 * k + 9 * q + tap) * 64 + cq * 4;  // uniform
                        acc[k] = fmaf(tv.x, wp[0], acc[k]);
                        acc[k] = fmaf(tv.y, wp[1], acc[k]);
                        acc[k] = fmaf(tv.z, wp[2], acc[k]);
                        acc[k] = fmaf(tv.w, wp[3], acc[k]);
                    }
                }
            }
        }
    }
    float m = acc[0];
    #pragma unroll
    for (int k = 1; k < 9; k++) m = fmaxf(m, acc[k]);
    float ex[9], s = 0.f;
    #pragma unroll
    for (int k = 0; k < 9; k++) { ex[k] = __expf(acc[k] - m); s += ex[k]; }
    float inv = 1.f / s;
    #pragma unroll
    for (int k = 0; k < 9; k++)
        kern[(size_t)(k * 4 + q) * NPX_ + px] = ex[k] * inv;
}

// ---------------- Kernel 3: G = w_out @ x (bf16 MFMA, low-res) ----------------
// grid 512 = n(4) * pxblk(128 of 128 px); 512 thr = 8 waves (2M x 4N)
// G stored as o-quads: [n][64][HW] of ushort4
__global__ __launch_bounds__(512, 4) void k_gemm(
    const float* __restrict__ x, const short* __restrict__ wob,
    unsigned short* __restrict__ Gq)
{
    __shared__ short Asm[2][256 * 40];   // 2 x 20 KB
    __shared__ short Bsm[2][128 * 40];   // 2 x 10 KB

    int tid = threadIdx.x;
    int bx = blockIdx.x;
    int n = bx >> 7;
    int px0 = (bx & 127) * 128;

    int lane = tid & 63;
    int wave = tid >> 6;
    int wm = wave >> 2, wn = wave & 3;

    int ao = tid >> 1, ah = tid & 1;     // A stage role
    int bpx = tid & 127, bcq = tid >> 7; // B stage role (px, 8-ch quarter)

    const float* xb = x + (size_t)n * C_ * HW_ + px0 + bpx;
    const short* wr = wob + ao * C_ + ah * 16;

    short8 a0, a1;
    float xg[8];

    auto issue = [&](int c0) {
        a0 = *(const short8*)(wr + c0);
        a1 = *(const short8*)(wr + c0 + 8);
        #pragma unroll
        for (int j = 0; j < 8; j++)
            xg[j] = xb[(size_t)(c0 + bcq * 8 + j) * HW_];
    };
    auto commit = [&](int buf) {
        short* ad = &Asm[buf][ao * 40 + ah * 16];
        *(short8*)ad = a0;
        *(short8*)(ad + 8) = a1;
        short8 bv;
        #pragma unroll
        for (int j = 0; j < 8; j++) bv[j] = (short)f2bf(xg[j]);
        *(short8*)&Bsm[buf][bpx * 40 + bcq * 8] = bv;
    };

    floatx4 acc[8][2];
    #pragma unroll
    for (int fm = 0; fm < 8; fm++) {
        acc[fm][0] = (floatx4)0.f;
        acc[fm][1] = (floatx4)0.f;
    }

    issue(0);
    commit(0);
    __syncthreads();

    for (int kc = 0; kc < 8; kc++) {
        int cur = kc & 1;
        if (kc < 7) issue((kc + 1) * 32);
        short8 bfrag[2];
        #pragma unroll
        for (int fn = 0; fn < 2; fn++) {
            int col = wn * 32 + fn * 16 + (lane & 15);
            bfrag[fn] = *(const short8*)&Bsm[cur][col * 40 + (lane >> 4) * 8];
        }
        #pragma unroll
        for (int fm = 0; fm < 8; fm++) {
            int row = wm * 128 + fm * 16 + (lane & 15);
            short8 af = *(const short8*)&Asm[cur][row * 40 + (lane >> 4) * 8];
            acc[fm][0] = __builtin_amdgcn_mfma_f32_16x16x32_bf16(af, bfrag[0], acc[fm][0], 0, 0, 0);
            acc[fm][1] = __builtin_amdgcn_mfma_f32_16x16x32_bf16(af, bfrag[1], acc[fm][1], 0, 0, 0);
        }
        if (kc < 7) {
            commit(cur ^ 1);
            __syncthreads();
        }
    }
    #pragma unroll
    for (int fm = 0; fm < 8; fm++) {
        int oq = wm * 32 + fm * 4 + (lane >> 4);   // o-quad index
        #pragma unroll
        for (int fn = 0; fn < 2; fn++) {
            int col = px0 + wn * 32 + fn * 16 + (lane & 15);
            ushort4v v;
            v.x = f2bf(acc[fm][fn][0]);
            v.y = f2bf(acc[fm][fn][1]);
            v.z = f2bf(acc[fm][fn][2]);
            v.w = f2bf(acc[fm][fn][3]);
            *(ushort4v*)&Gq[(((size_t)n * 64 + oq) * HW_ + col) * 4] = v;
        }
    }
}

// ---------------- Kernel 4: 9-tap combine + pixel shuffle + bias ----------------
// grid 2048; bx = (n*64 + og*8 + hbhi)*8 + (hb&7) -> og-siblings same XCD.
__global__ __launch_bounds__(256) void k_up(
    const unsigned short* __restrict__ Gq, const float* __restrict__ kern,
    const float* __restrict__ bo, float* __restrict__ y)
{
    int bx = blockIdx.x;
    int x7 = bx & 7;
    int g  = bx >> 3;
    int hbhi = g & 7;
    int og = (g >> 3) & 7;
    int n  = g >> 6;
    int hb = hbhi * 8 + x7;

    int tid = threadIdx.x;
    int h = hb * 2 + (tid >> 7);
    int w = tid & 127;
    int idxp = n * HW_ + h * W_ + w;

    // per-pixel kernel weights from planes: 36 coalesced dword loads
    float kv[36];
    #pragma unroll
    for (int e = 0; e < E_; e++)
        kv[e] = kern[(size_t)e * NPX_ + idxp];

    // tap offsets (clamped) + validity
    int off[9]; bool val[9];
    #pragma unroll
    for (int di = 0; di < 3; di++) {
        int hh = h + di - 1;
        bool hvv = (hh >= 0 && hh < H_);
        int hc = hvv ? hh : h;
        #pragma unroll
        for (int dj = 0; dj < 3; dj++) {
            int ww = w + dj - 1;
            bool wvv = (ww >= 0 && ww < W_);
            int wc = wvv ? ww : w;
            off[di * 3 + dj] = hc * W_ + wc;
            val[di * 3 + dj] = hvv && wvv;
        }
    }

    const unsigned short* Gb = Gq + ((size_t)n * 64 + og * 8) * HW_ * 4;
    size_t ybase = ((size_t)n * OC_ + og * 32) * (4 * HW_) + (size_t)(2 * h) * 256 + 2 * w;

    #pragma unroll 2
    for (int j = 0; j < 8; j++) {           // o-quads within og
        const unsigned short* Gj = Gb + (size_t)j * HW_ * 4;
        float b0 = bo[og * 32 + j * 4 + 0];
        float b1 = bo[og * 32 + j * 4 + 1];
        float b2 = bo[og * 32 + j * 4 + 2];
        float b3 = bo[og * 32 + j * 4 + 3];
        float a[4][4];
        #pragma unroll
        for (int s = 0; s < 4; s++) { a[0][s] = b0; a[1][s] = b1; a[2][s] = b2; a[3][s] = b3; }
        #pragma unroll
        for (int k = 0; k < 9; k++) {
            ushort4v gv = *(const ushort4v*)(Gj + (size_t)off[k] * 4);
            float g0 = val[k] ? bf2f(gv.x) : 0.f;
            float g1 = val[k] ? bf2f(gv.y) : 0.f;
            float g2 = val[k] ? bf2f(gv.z) : 0.f;
            float g3 = val[k] ? bf2f(gv.w) : 0.f;
            #pragma unroll
            for (int s = 0; s < 4; s++) {
                float kw = kv[k * 4 + s];
                a[0][s] = fmaf(g0, kw, a[0][s]);
                a[1][s] = fmaf(g1, kw, a[1][s]);
                a[2][s] = fmaf(g2, kw, a[2][s]);
                a[3][s] = fmaf(g3, kw, a[3][s]);
            }
        }
        #pragma unroll
        for (int i = 0; i < 4; i++) {
            float* yp = y + ybase + (size_t)(j * 4 + i) * (4 * HW_);
            float2 r0; r0.x = a[i][0]; r0.y = a[i][1];
            float2 r1; r1.x = a[i][2]; r1.y = a[i][3];
            *(float2*)yp = r0;
            *(float2*)(yp + 256) = r1;
        }
    }
}

extern "C" void kernel_launch(void* const* d_in, const int* in_sizes, int n_in,
                              void* d_out, int out_size, void* d_ws, size_t ws_size,
                              hipStream_t stream) {
    const float* x  = (const float*)d_in[0];
    const float* wd = (const float*)d_in[1];
    const float* bd = (const float*)d_in[2];
    const float* we = (const float*)d_in[3];
    const float* be = (const float*)d_in[4];
    const float* wo = (const float*)d_in[5];
    const float* bo = (const float*)d_in[6];
    float* y = (float*)d_out;

    float* t    = (float*)d_ws;                        // [NPX][64] f32   = 16.8 MB
    float* kern = t + (size_t)NPX_ * 64;               // [36][NPX] f32   =  9.4 MB
    short* wob  = (short*)(kern + (size_t)E_ * NPX_);  // 256*256 bf16    = 128 KB
    float* weT  = (float*)(wob + (size_t)OC_ * C_);    // [36][9][64] f32 =  83 KB
    unsigned short* Gq = (unsigned short*)(weT + E_ * 9 * 64);  // 33.5 MB

    k_prep<<<145,  256, 0, stream>>>(wo, wob, we, weT);
    k_down<<<512,  512, 0, stream>>>(x, wd, bd, t);
    k_enc <<<1024, 256, 0, stream>>>(t, weT, be, kern);
    k_gemm<<<512,  512, 0, stream>>>(x, wob, Gq);
    k_up  <<<2048, 256, 0, stream>>>(Gq, kern, bo, y);
}

// Round 7
// 148.940 us; speedup vs baseline: 2.1153x; 2.1153x over previous
//
#include <hip/hip_runtime.h>
#include <hip/hip_bf16.h>
#include <stddef.h>

typedef __attribute__((ext_vector_type(8))) short short8;
typedef __attribute__((ext_vector_type(4))) short short4v;
typedef __attribute__((ext_vector_type(4))) unsigned short ushort4v;
typedef __attribute__((ext_vector_type(4))) float floatx4;

#define N_ 4
#define C_ 256
#define H_ 128
#define W_ 128
#define HW_ (H_*W_)
#define NPX_ (N_*HW_)   // 65536
#define CD_ 64     // C/4
#define E_ 36      // k2*up2
#define OC_ 256

// round-to-nearest-even f32 -> bf16 bits
static __device__ __forceinline__ unsigned short f2bf(float f) {
    union { float f; unsigned u; } v; v.f = f;
    unsigned r = v.u + 0x7fff + ((v.u >> 16) & 1);
    return (unsigned short)(r >> 16);
}
static __device__ __forceinline__ float bf2f(unsigned short s) {
    union { unsigned u; float f; } v; v.u = ((unsigned)s) << 16;
    return v.f;
}

// ---------------- Kernel 0: w_out -> bf16 ; w_enc -> wBT[48][576] bf16 ----------------
// wBT[n][k]: k = tap*64 + c ; n = e (rows 36..47 zero)
__global__ __launch_bounds__(256) void k_prep(const float* __restrict__ wo,
                                              short* __restrict__ wob,
                                              const float* __restrict__ we,
                                              unsigned short* __restrict__ wBT) {
    int bx = blockIdx.x;
    if (bx < 64) {
        int i = (bx * 256 + threadIdx.x) * 4;
        float4 v = *(const float4*)&wo[i];
        short4v s;
        s.x = (short)f2bf(v.x); s.y = (short)f2bf(v.y);
        s.z = (short)f2bf(v.z); s.w = (short)f2bf(v.w);
        *(short4v*)&wob[i] = s;
    } else {
        int idx = (bx - 64) * 256 + threadIdx.x;   // < 48*576 = 27648
        if (idx < 48 * 576) {
            int e = idx / 576;
            int k = idx - e * 576;
            int tap = k >> 6, c = k & 63;
            float v = (e < E_) ? we[((size_t)e * 64 + c) * 9 + tap] : 0.f;
            wBT[idx] = f2bf(v);
        }
    }
}

// ---------------- Kernel 1: 1x1 down conv as f32 GEMM, bf16 channel-last out ----------------
// grid 512 = n(4) * pxchunk(128 of 128px); 512 thr; tile M=64 x N=128, K=256/32
// t layout: [n*HW + px][64] bf16
#define WST 68
#define XST 132
__global__ __launch_bounds__(512) void k_down(
    const float* __restrict__ x, const float* __restrict__ wd,
    const float* __restrict__ bd, unsigned short* __restrict__ t)
{
    __shared__ float Wsm[32 * WST];   // [k][o]  8.7 KB
    __shared__ float Xs[32 * XST];    // [k][px] 16.9 KB
    int tid = threadIdx.x;
    int bx = blockIdx.x;
    int n = bx >> 7;
    int px0 = (bx & 127) * 128;
    int mg = tid & 15;               // o-quad (fast-varying for coalesced store)
    int ng = tid >> 4;               // px group of 4
    float acc[4][4];
    #pragma unroll
    for (int i = 0; i < 4; i++)
        #pragma unroll
        for (int j = 0; j < 4; j++) acc[i][j] = 0.f;

    for (int c0 = 0; c0 < C_; c0 += 32) {
        {
            int o = tid >> 3, kb = tid & 7;
            float4 wv = *(const float4*)&wd[o * C_ + c0 + kb * 4];
            Wsm[(kb * 4 + 0) * WST + o] = wv.x;
            Wsm[(kb * 4 + 1) * WST + o] = wv.y;
            Wsm[(kb * 4 + 2) * WST + o] = wv.z;
            Wsm[(kb * 4 + 3) * WST + o] = wv.w;
        }
        {
            int c = tid >> 4, pg = tid & 15;
            const float* xp = &x[((size_t)n * C_ + c0 + c) * HW_ + px0 + pg * 8];
            #pragma unroll
            for (int i = 0; i < 2; i++) {
                float4 v = *(const float4*)(xp + i * 4);
                *(float4*)&Xs[c * XST + pg * 8 + i * 4] = v;
            }
        }
        __syncthreads();
        #pragma unroll 4
        for (int k = 0; k < 32; k++) {
            float4 wv = *(const float4*)&Wsm[k * WST + mg * 4];
            float4 xv = *(const float4*)&Xs[k * XST + ng * 4];
            float xs[4] = {xv.x, xv.y, xv.z, xv.w};
            float ws[4] = {wv.x, wv.y, wv.z, wv.w};
            #pragma unroll
            for (int i = 0; i < 4; i++)
                #pragma unroll
                for (int j = 0; j < 4; j++)
                    acc[i][j] = fmaf(ws[i], xs[j], acc[i][j]);
        }
        __syncthreads();
    }
    float b0 = bd[mg * 4 + 0], b1 = bd[mg * 4 + 1], b2 = bd[mg * 4 + 2], b3 = bd[mg * 4 + 3];
    #pragma unroll
    for (int j = 0; j < 4; j++) {
        ushort4v r;
        r.x = f2bf(acc[0][j] + b0);
        r.y = f2bf(acc[1][j] + b1);
        r.z = f2bf(acc[2][j] + b2);
        r.w = f2bf(acc[3][j] + b3);
        *(ushort4v*)&t[((size_t)n * HW_ + px0 + ng * 4 + j) * 64 + mg * 4] = r;
    }
}

// ---------------- Kernel 2: enc conv as MFMA GEMM + softmax ----------------
// grid 1024 = n(4)*h(128)*half(2); 256 thr = 4 waves; M=64 px, N=48 (36 used), K=576.
// t halo tile [3][66][64] bf16 in LDS, XOR-swizzled (us ^= (r&7)<<3).
__global__ __launch_bounds__(256) void k_enc(
    const unsigned short* __restrict__ t, const unsigned short* __restrict__ wBT,
    const float* __restrict__ be, float* __restrict__ kern)
{
    __shared__ unsigned short Tl[198 * 64];  // 25.3 KB
    __shared__ float El[64 * 48];            // 12.3 KB

    int bx = blockIdx.x;
    int n = bx >> 8, h = (bx >> 1) & 127, wh = bx & 1;
    int w0 = wh * 64;
    int tid = threadIdx.x;

    // stage t halo tile (rows r = di*66 + (ww-local), 128 B each, zero-padded)
    for (int idx = tid; idx < 1584; idx += 256) {
        int r = idx >> 3, ch = idx & 7;
        int di = r / 66, rr = r - di * 66;
        int hh = h + di - 1, ww = w0 + rr - 1;
        short8 v = {0,0,0,0,0,0,0,0};
        if (hh >= 0 && hh < H_ && ww >= 0 && ww < W_)
            v = *(const short8*)&t[((size_t)(n * H_ + hh) * W_ + ww) * 64 + ch * 8];
        int us = (r * 64 + ch * 8) ^ ((r & 7) << 3);
        *(short8*)&Tl[us] = v;
    }
    __syncthreads();

    int lane = tid & 63, wave = tid >> 6;
    int m0 = wave * 16;    // this wave's px base

    floatx4 acc[3];
    acc[0] = (floatx4)0.f; acc[1] = (floatx4)0.f; acc[2] = (floatx4)0.f;

    int pxl = m0 + (lane & 15);
    int kq = (lane >> 4) * 8;
    #pragma unroll
    for (int kc = 0; kc < 18; kc++) {
        const int tap = kc >> 1, chalf = kc & 1;
        const int di = tap / 3, dj = tap % 3;
        int r = di * 66 + pxl + dj;
        int us = (r * 64 + chalf * 32 + kq) ^ ((r & 7) << 3);
        short8 af = *(const short8*)&Tl[us];
        #pragma unroll
        for (int fn = 0; fn < 3; fn++) {
            int nn = fn * 16 + (lane & 15);
            short8 bf = *(const short8*)&wBT[(size_t)nn * 576 + kc * 32 + kq];
            acc[fn] = __builtin_amdgcn_mfma_f32_16x16x32_bf16(af, bf, acc[fn], 0, 0, 0);
        }
    }
    // logits -> LDS
    #pragma unroll
    for (int fn = 0; fn < 3; fn++)
        #pragma unroll
        for (int i = 0; i < 4; i++) {
            int px = m0 + (lane >> 4) * 4 + i;
            El[px * 48 + fn * 16 + (lane & 15)] = acc[fn][i];
        }
    __syncthreads();

    // softmax over k (stride 4) per (px, q); write kern planes
    int sp = tid >> 2, q = tid & 3;
    float l[9];
    #pragma unroll
    for (int k = 0; k < 9; k++) l[k] = El[sp * 48 + k * 4 + q] + be[k * 4 + q];
    float m = l[0];
    #pragma unroll
    for (int k = 1; k < 9; k++) m = fmaxf(m, l[k]);
    float ex[9], s = 0.f;
    #pragma unroll
    for (int k = 0; k < 9; k++) { ex[k] = __expf(l[k] - m); s += ex[k]; }
    float inv = 1.f / s;
    int pxg = n * HW_ + h * W_ + w0 + sp;
    #pragma unroll
    for (int k = 0; k < 9; k++)
        kern[(size_t)(k * 4 + q) * NPX_ + pxg] = ex[k] * inv;
}

// ---------------- Kernel 3: G = w_out @ x (bf16 MFMA, low-res) ----------------
// grid 512 = n(4) * pxblk(128 of 128 px); 512 thr = 8 waves (2M x 4N)
// G stored as o-quads: [n][64][HW] of ushort4
__global__ __launch_bounds__(512, 4) void k_gemm(
    const float* __restrict__ x, const short* __restrict__ wob,
    unsigned short* __restrict__ Gq)
{
    __shared__ short Asm[2][256 * 40];   // 2 x 20 KB
    __shared__ short Bsm[2][128 * 40];   // 2 x 10 KB

    int tid = threadIdx.x;
    int bx = blockIdx.x;
    int n = bx >> 7;
    int px0 = (bx & 127) * 128;

    int lane = tid & 63;
    int wave = tid >> 6;
    int wm = wave >> 2, wn = wave & 3;

    int ao = tid >> 1, ah = tid & 1;     // A stage role
    int bpx = tid & 127, bcq = tid >> 7; // B stage role (px, 8-ch quarter)

    const float* xb = x + (size_t)n * C_ * HW_ + px0 + bpx;
    const short* wr = wob + ao * C_ + ah * 16;

    short8 a0, a1;
    float xg[8];

    auto issue = [&](int c0) {
        a0 = *(const short8*)(wr + c0);
        a1 = *(const short8*)(wr + c0 + 8);
        #pragma unroll
        for (int j = 0; j < 8; j++)
            xg[j] = xb[(size_t)(c0 + bcq * 8 + j) * HW_];
    };
    auto commit = [&](int buf) {
        short* ad = &Asm[buf][ao * 40 + ah * 16];
        *(short8*)ad = a0;
        *(short8*)(ad + 8) = a1;
        short8 bv;
        #pragma unroll
        for (int j = 0; j < 8; j++) bv[j] = (short)f2bf(xg[j]);
        *(short8*)&Bsm[buf][bpx * 40 + bcq * 8] = bv;
    };

    floatx4 acc[8][2];
    #pragma unroll
    for (int fm = 0; fm < 8; fm++) {
        acc[fm][0] = (floatx4)0.f;
        acc[fm][1] = (floatx4)0.f;
    }

    issue(0);
    commit(0);
    __syncthreads();

    for (int kc = 0; kc < 8; kc++) {
        int cur = kc & 1;
        if (kc < 7) issue((kc + 1) * 32);
        short8 bfrag[2];
        #pragma unroll
        for (int fn = 0; fn < 2; fn++) {
            int col = wn * 32 + fn * 16 + (lane & 15);
            bfrag[fn] = *(const short8*)&Bsm[cur][col * 40 + (lane >> 4) * 8];
        }
        #pragma unroll
        for (int fm = 0; fm < 8; fm++) {
            int row = wm * 128 + fm * 16 + (lane & 15);
            short8 af = *(const short8*)&Asm[cur][row * 40 + (lane >> 4) * 8];
            acc[fm][0] = __builtin_amdgcn_mfma_f32_16x16x32_bf16(af, bfrag[0], acc[fm][0], 0, 0, 0);
            acc[fm][1] = __builtin_amdgcn_mfma_f32_16x16x32_bf16(af, bfrag[1], acc[fm][1], 0, 0, 0);
        }
        if (kc < 7) {
            commit(cur ^ 1);
            __syncthreads();
        }
    }
    #pragma unroll
    for (int fm = 0; fm < 8; fm++) {
        int oq = wm * 32 + fm * 4 + (lane >> 4);   // o-quad index
        #pragma unroll
        for (int fn = 0; fn < 2; fn++) {
            int col = px0 + wn * 32 + fn * 16 + (lane & 15);
            ushort4v v;
            v.x = f2bf(acc[fm][fn][0]);
            v.y = f2bf(acc[fm][fn][1]);
            v.z = f2bf(acc[fm][fn][2]);
            v.w = f2bf(acc[fm][fn][3]);
            *(ushort4v*)&Gq[(((size_t)n * 64 + oq) * HW_ + col) * 4] = v;
        }
    }
}

// ---------------- Kernel 4: 9-tap combine + pixel shuffle + bias ----------------
// grid 2048; bx = (n*64 + og*8 + hbhi)*8 + (hb&7) -> og-siblings same XCD.
__global__ __launch_bounds__(256) void k_up(
    const unsigned short* __restrict__ Gq, const float* __restrict__ kern,
    const float* __restrict__ bo, float* __restrict__ y)
{
    int bx = blockIdx.x;
    int x7 = bx & 7;
    int g  = bx >> 3;
    int hbhi = g & 7;
    int og = (g >> 3) & 7;
    int n  = g >> 6;
    int hb = hbhi * 8 + x7;

    int tid = threadIdx.x;
    int h = hb * 2 + (tid >> 7);
    int w = tid & 127;
    int idxp = n * HW_ + h * W_ + w;

    float kv[36];
    #pragma unroll
    for (int e = 0; e < E_; e++)
        kv[e] = kern[(size_t)e * NPX_ + idxp];

    int off[9]; bool val[9];
    #pragma unroll
    for (int di = 0; di < 3; di++) {
        int hh = h + di - 1;
        bool hvv = (hh >= 0 && hh < H_);
        int hc = hvv ? hh : h;
        #pragma unroll
        for (int dj = 0; dj < 3; dj++) {
            int ww = w + dj - 1;
            bool wvv = (ww >= 0 && ww < W_);
            int wc = wvv ? ww : w;
            off[di * 3 + dj] = hc * W_ + wc;
            val[di * 3 + dj] = hvv && wvv;
        }
    }

    const unsigned short* Gb = Gq + ((size_t)n * 64 + og * 8) * HW_ * 4;
    size_t ybase = ((size_t)n * OC_ + og * 32) * (4 * HW_) + (size_t)(2 * h) * 256 + 2 * w;

    #pragma unroll 2
    for (int j = 0; j < 8; j++) {           // o-quads within og
        const unsigned short* Gj = Gb + (size_t)j * HW_ * 4;
        float b0 = bo[og * 32 + j * 4 + 0];
        float b1 = bo[og * 32 + j * 4 + 1];
        float b2 = bo[og * 32 + j * 4 + 2];
        float b3 = bo[og * 32 + j * 4 + 3];
        float a[4][4];
        #pragma unroll
        for (int s = 0; s < 4; s++) { a[0][s] = b0; a[1][s] = b1; a[2][s] = b2; a[3][s] = b3; }
        #pragma unroll
        for (int k = 0; k < 9; k++) {
            ushort4v gv = *(const ushort4v*)(Gj + (size_t)off[k] * 4);
            float g0 = val[k] ? bf2f(gv.x) : 0.f;
            float g1 = val[k] ? bf2f(gv.y) : 0.f;
            float g2 = val[k] ? bf2f(gv.z) : 0.f;
            float g3 = val[k] ? bf2f(gv.w) : 0.f;
            #pragma unroll
            for (int s = 0; s < 4; s++) {
                float kw = kv[k * 4 + s];
                a[0][s] = fmaf(g0, kw, a[0][s]);
                a[1][s] = fmaf(g1, kw, a[1][s]);
                a[2][s] = fmaf(g2, kw, a[2][s]);
                a[3][s] = fmaf(g3, kw, a[3][s]);
            }
        }
        #pragma unroll
        for (int i = 0; i < 4; i++) {
            float* yp = y + ybase + (size_t)(j * 4 + i) * (4 * HW_);
            float2 r0; r0.x = a[i][0]; r0.y = a[i][1];
            float2 r1; r1.x = a[i][2]; r1.y = a[i][3];
            *(float2*)yp = r0;
            *(float2*)(yp + 256) = r1;
        }
    }
}

extern "C" void kernel_launch(void* const* d_in, const int* in_sizes, int n_in,
                              void* d_out, int out_size, void* d_ws, size_t ws_size,
                              hipStream_t stream) {
    const float* x  = (const float*)d_in[0];
    const float* wd = (const float*)d_in[1];
    const float* bd = (const float*)d_in[2];
    const float* we = (const float*)d_in[3];
    const float* be = (const float*)d_in[4];
    const float* wo = (const float*)d_in[5];
    const float* bo = (const float*)d_in[6];
    float* y = (float*)d_out;

    unsigned short* t = (unsigned short*)d_ws;             // [NPX][64] bf16 = 8.4 MB
    float* kern = (float*)(t + (size_t)NPX_ * 64);         // [36][NPX] f32  = 9.4 MB
    short* wob  = (short*)(kern + (size_t)E_ * NPX_);      // 256*256 bf16
    unsigned short* wBT = (unsigned short*)(wob + (size_t)OC_ * C_);  // [48][576] bf16
    unsigned short* Gq  = wBT + (size_t)48 * 576;          // 33.5 MB

    k_prep<<<172,  256, 0, stream>>>(wo, wob, we, wBT);
    k_down<<<512,  512, 0, stream>>>(x, wd, bd, t);
    k_enc <<<1024, 256, 0, stream>>>(t, wBT, be, kern);
    k_gemm<<<512,  512, 0, stream>>>(x, wob, Gq);
    k_up  <<<2048, 256, 0, stream>>>(Gq, kern, bo, y);
}

// Round 8
// 148.789 us; speedup vs baseline: 2.1175x; 1.0010x over previous
//
#include <hip/hip_runtime.h>
#include <hip/hip_bf16.h>
#include <stddef.h>

typedef __attribute__((ext_vector_type(8))) short short8;
typedef __attribute__((ext_vector_type(4))) short short4v;
typedef __attribute__((ext_vector_type(4))) unsigned short ushort4v;
typedef __attribute__((ext_vector_type(4))) float floatx4;

#define N_ 4
#define C_ 256
#define H_ 128
#define W_ 128
#define HW_ (H_*W_)
#define NPX_ (N_*HW_)   // 65536
#define E_ 36      // k2*up2
#define OC_ 256

// round-to-nearest-even f32 -> bf16 bits
static __device__ __forceinline__ unsigned short f2bf(float f) {
    union { float f; unsigned u; } v; v.f = f;
    unsigned r = v.u + 0x7fff + ((v.u >> 16) & 1);
    return (unsigned short)(r >> 16);
}
static __device__ __forceinline__ float bf2f(unsigned short s) {
    union { unsigned u; float f; } v; v.u = ((unsigned)s) << 16;
    return v.f;
}

// ---------------- Kernel 0: build wcomb[320][256] bf16 (w_out ++ w_down) ; wBT[48][576] bf16 ----------------
__global__ __launch_bounds__(256) void k_prep(const float* __restrict__ wo,
                                              const float* __restrict__ wd,
                                              short* __restrict__ wcomb,
                                              const float* __restrict__ we,
                                              unsigned short* __restrict__ wBT) {
    int bx = blockIdx.x;
    if (bx < 80) {
        int i = (bx * 256 + threadIdx.x) * 4;   // < 81920
        int row = i >> 8, c = i & 255;
        const float* src = (row < 256) ? &wo[row * 256 + c] : &wd[(row - 256) * 256 + c];
        float4 v = *(const float4*)src;
        short4v s;
        s.x = (short)f2bf(v.x); s.y = (short)f2bf(v.y);
        s.z = (short)f2bf(v.z); s.w = (short)f2bf(v.w);
        *(short4v*)&wcomb[i] = s;
    } else {
        int idx = (bx - 80) * 256 + threadIdx.x;   // < 48*576 = 27648
        if (idx < 48 * 576) {
            int e = idx / 576;
            int k = idx - e * 576;
            int tap = k >> 6, c = k & 63;
            float v = (e < E_) ? we[((size_t)e * 64 + c) * 9 + tap] : 0.f;
            wBT[idx] = f2bf(v);
        }
    }
}

// ---------------- Kernel 1 (fused): [G; t] = wcomb @ x (bf16 MFMA) ----------------
// grid 512 = n(4) * pxblk(128 of 128 px); 512 thr = 8 waves (2M x 4N)
// M=320 (256 -> G o-quads, 64 -> t channel-last +bias), N=128 px, K=256/32.
__global__ __launch_bounds__(512, 3) void k_gemm(
    const float* __restrict__ x, const short* __restrict__ wcomb,
    const float* __restrict__ bd,
    unsigned short* __restrict__ Gq, unsigned short* __restrict__ t)
{
    __shared__ short Asm[2][320 * 40];   // 2 x 25 KB
    __shared__ short Bsm[2][128 * 40];   // 2 x 10 KB   (total 70 KB -> 2 blocks/CU)

    int tid = threadIdx.x;
    int bx = blockIdx.x;
    int n = bx >> 7;
    int px0 = (bx & 127) * 128;

    int lane = tid & 63;
    int wave = tid >> 6;
    int wm = wave >> 2, wn = wave & 3;

    int ao = tid >> 1, ah = tid & 1;     // A stage role (rows 0..255)
    int bpx = tid & 127, bcq = tid >> 7; // B stage role (px, 8-ch quarter)
    bool hasExtra = (tid < 128);         // rows 256..319 (64 rows x 2 halves)

    const float* xb = x + (size_t)n * C_ * HW_ + px0 + bpx;
    const short* wr  = wcomb + ao * C_ + ah * 16;
    const short* wr2 = wcomb + (256 + (tid >> 1)) * C_ + (tid & 1) * 16;

    short8 a0, a1, a2, a3;
    float xg[8];

    auto issue = [&](int c0) {
        a0 = *(const short8*)(wr + c0);
        a1 = *(const short8*)(wr + c0 + 8);
        if (hasExtra) {
            a2 = *(const short8*)(wr2 + c0);
            a3 = *(const short8*)(wr2 + c0 + 8);
        }
        #pragma unroll
        for (int j = 0; j < 8; j++)
            xg[j] = xb[(size_t)(c0 + bcq * 8 + j) * HW_];
    };
    auto commit = [&](int buf) {
        short* ad = &Asm[buf][ao * 40 + ah * 16];
        *(short8*)ad = a0;
        *(short8*)(ad + 8) = a1;
        if (hasExtra) {
            short* ad2 = &Asm[buf][(256 + (tid >> 1)) * 40 + (tid & 1) * 16];
            *(short8*)ad2 = a2;
            *(short8*)(ad2 + 8) = a3;
        }
        short8 bv;
        #pragma unroll
        for (int j = 0; j < 8; j++) bv[j] = (short)f2bf(xg[j]);
        *(short8*)&Bsm[buf][bpx * 40 + bcq * 8] = bv;
    };

    floatx4 acc[10][2];
    #pragma unroll
    for (int fm = 0; fm < 10; fm++) {
        acc[fm][0] = (floatx4)0.f;
        acc[fm][1] = (floatx4)0.f;
    }

    issue(0);
    commit(0);
    __syncthreads();

    for (int kc = 0; kc < 8; kc++) {
        int cur = kc & 1;
        if (kc < 7) issue((kc + 1) * 32);
        short8 bfrag[2];
        #pragma unroll
        for (int fn = 0; fn < 2; fn++) {
            int col = wn * 32 + fn * 16 + (lane & 15);
            bfrag[fn] = *(const short8*)&Bsm[cur][col * 40 + (lane >> 4) * 8];
        }
        #pragma unroll
        for (int fm = 0; fm < 10; fm++) {
            int rbase = (fm < 8) ? (wm * 128 + fm * 16) : (256 + wm * 32 + (fm - 8) * 16);
            int row = rbase + (lane & 15);
            short8 af = *(const short8*)&Asm[cur][row * 40 + (lane >> 4) * 8];
            acc[fm][0] = __builtin_amdgcn_mfma_f32_16x16x32_bf16(af, bfrag[0], acc[fm][0], 0, 0, 0);
            acc[fm][1] = __builtin_amdgcn_mfma_f32_16x16x32_bf16(af, bfrag[1], acc[fm][1], 0, 0, 0);
        }
        if (kc < 7) {
            commit(cur ^ 1);
            __syncthreads();
        }
    }
    // epilogue 1: G o-quads (rows 0..255)
    #pragma unroll
    for (int fm = 0; fm < 8; fm++) {
        int oq = wm * 32 + fm * 4 + (lane >> 4);
        #pragma unroll
        for (int fn = 0; fn < 2; fn++) {
            int col = px0 + wn * 32 + fn * 16 + (lane & 15);
            ushort4v v;
            v.x = f2bf(acc[fm][fn][0]);
            v.y = f2bf(acc[fm][fn][1]);
            v.z = f2bf(acc[fm][fn][2]);
            v.w = f2bf(acc[fm][fn][3]);
            *(ushort4v*)&Gq[(((size_t)n * 64 + oq) * HW_ + col) * 4] = v;
        }
    }
    // epilogue 2: t channel-last + bias (rows 256..319)
    #pragma unroll
    for (int f8 = 0; f8 < 2; f8++) {
        int ot = wm * 32 + f8 * 16 + ((lane >> 4) << 2);
        float b0 = bd[ot + 0], b1 = bd[ot + 1], b2 = bd[ot + 2], b3 = bd[ot + 3];
        #pragma unroll
        for (int fn = 0; fn < 2; fn++) {
            int col = px0 + wn * 32 + fn * 16 + (lane & 15);
            ushort4v r;
            r.x = f2bf(acc[8 + f8][fn][0] + b0);
            r.y = f2bf(acc[8 + f8][fn][1] + b1);
            r.z = f2bf(acc[8 + f8][fn][2] + b2);
            r.w = f2bf(acc[8 + f8][fn][3] + b3);
            *(ushort4v*)&t[((size_t)n * HW_ + col) * 64 + ot] = r;
        }
    }
}

// ---------------- Kernel 2: enc conv as MFMA GEMM + softmax ----------------
// grid 1024 = n(4)*h(128)*half(2); 256 thr = 4 waves; M=64 px, N=48 (36 used), K=576.
__global__ __launch_bounds__(256) void k_enc(
    const unsigned short* __restrict__ t, const unsigned short* __restrict__ wBT,
    const float* __restrict__ be, float* __restrict__ kern)
{
    __shared__ unsigned short Tl[198 * 64];  // 25.3 KB
    __shared__ float El[64 * 48];            // 12.3 KB

    int bx = blockIdx.x;
    int n = bx >> 8, h = (bx >> 1) & 127, wh = bx & 1;
    int w0 = wh * 64;
    int tid = threadIdx.x;

    for (int idx = tid; idx < 1584; idx += 256) {
        int r = idx >> 3, ch = idx & 7;
        int di = r / 66, rr = r - di * 66;
        int hh = h + di - 1, ww = w0 + rr - 1;
        short8 v = {0,0,0,0,0,0,0,0};
        if (hh >= 0 && hh < H_ && ww >= 0 && ww < W_)
            v = *(const short8*)&t[((size_t)(n * H_ + hh) * W_ + ww) * 64 + ch * 8];
        int us = (r * 64 + ch * 8) ^ ((r & 7) << 3);
        *(short8*)&Tl[us] = v;
    }
    __syncthreads();

    int lane = tid & 63, wave = tid >> 6;
    int m0 = wave * 16;

    floatx4 acc[3];
    acc[0] = (floatx4)0.f; acc[1] = (floatx4)0.f; acc[2] = (floatx4)0.f;

    int pxl = m0 + (lane & 15);
    int kq = (lane >> 4) * 8;
    #pragma unroll
    for (int kc = 0; kc < 18; kc++) {
        const int tap = kc >> 1, chalf = kc & 1;
        const int di = tap / 3, dj = tap % 3;
        int r = di * 66 + pxl + dj;
        int us = (r * 64 + chalf * 32 + kq) ^ ((r & 7) << 3);
        short8 af = *(const short8*)&Tl[us];
        #pragma unroll
        for (int fn = 0; fn < 3; fn++) {
            int nn = fn * 16 + (lane & 15);
            short8 bf = *(const short8*)&wBT[(size_t)nn * 576 + kc * 32 + kq];
            acc[fn] = __builtin_amdgcn_mfma_f32_16x16x32_bf16(af, bf, acc[fn], 0, 0, 0);
        }
    }
    #pragma unroll
    for (int fn = 0; fn < 3; fn++)
        #pragma unroll
        for (int i = 0; i < 4; i++) {
            int px = m0 + (lane >> 4) * 4 + i;
            El[px * 48 + fn * 16 + (lane & 15)] = acc[fn][i];
        }
    __syncthreads();

    int sp = tid >> 2, q = tid & 3;
    float l[9];
    #pragma unroll
    for (int k = 0; k < 9; k++) l[k] = El[sp * 48 + k * 4 + q] + be[k * 4 + q];
    float m = l[0];
    #pragma unroll
    for (int k = 1; k < 9; k++) m = fmaxf(m, l[k]);
    float ex[9], s = 0.f;
    #pragma unroll
    for (int k = 0; k < 9; k++) { ex[k] = __expf(l[k] - m); s += ex[k]; }
    float inv = 1.f / s;
    int pxg = n * HW_ + h * W_ + w0 + sp;
    #pragma unroll
    for (int k = 0; k < 9; k++)
        kern[(size_t)(k * 4 + q) * NPX_ + pxg] = ex[k] * inv;
}

// ---------------- Kernel 3: 9-tap combine + pixel shuffle + bias ----------------
// grid 2048; bx = (n*64 + og*8 + hbhi)*8 + (hb&7) -> og-siblings same XCD.
__global__ __launch_bounds__(256) void k_up(
    const unsigned short* __restrict__ Gq, const float* __restrict__ kern,
    const float* __restrict__ bo, float* __restrict__ y)
{
    int bx = blockIdx.x;
    int x7 = bx & 7;
    int g  = bx >> 3;
    int hbhi = g & 7;
    int og = (g >> 3) & 7;
    int n  = g >> 6;
    int hb = hbhi * 8 + x7;

    int tid = threadIdx.x;
    int h = hb * 2 + (tid >> 7);
    int w = tid & 127;
    int idxp = n * HW_ + h * W_ + w;

    float kv[36];
    #pragma unroll
    for (int e = 0; e < E_; e++)
        kv[e] = kern[(size_t)e * NPX_ + idxp];

    int off[9]; bool val[9];
    #pragma unroll
    for (int di = 0; di < 3; di++) {
        int hh = h + di - 1;
        bool hvv = (hh >= 0 && hh < H_);
        int hc = hvv ? hh : h;
        #pragma unroll
        for (int dj = 0; dj < 3; dj++) {
            int ww = w + dj - 1;
            bool wvv = (ww >= 0 && ww < W_);
            int wc = wvv ? ww : w;
            off[di * 3 + dj] = hc * W_ + wc;
            val[di * 3 + dj] = hvv && wvv;
        }
    }

    const unsigned short* Gb = Gq + ((size_t)n * 64 + og * 8) * HW_ * 4;
    size_t ybase = ((size_t)n * OC_ + og * 32) * (4 * HW_) + (size_t)(2 * h) * 256 + 2 * w;

    #pragma unroll 2
    for (int j = 0; j < 8; j++) {
        const unsigned short* Gj = Gb + (size_t)j * HW_ * 4;
        float b0 = bo[og * 32 + j * 4 + 0];
        float b1 = bo[og * 32 + j * 4 + 1];
        float b2 = bo[og * 32 + j * 4 + 2];
        float b3 = bo[og * 32 + j * 4 + 3];
        float a[4][4];
        #pragma unroll
        for (int s = 0; s < 4; s++) { a[0][s] = b0; a[1][s] = b1; a[2][s] = b2; a[3][s] = b3; }
        #pragma unroll
        for (int k = 0; k < 9; k++) {
            ushort4v gv = *(const ushort4v*)(Gj + (size_t)off[k] * 4);
            float g0 = val[k] ? bf2f(gv.x) : 0.f;
            float g1 = val[k] ? bf2f(gv.y) : 0.f;
            float g2 = val[k] ? bf2f(gv.z) : 0.f;
            float g3 = val[k] ? bf2f(gv.w) : 0.f;
            #pragma unroll
            for (int s = 0; s < 4; s++) {
                float kw = kv[k * 4 + s];
                a[0][s] = fmaf(g0, kw, a[0][s]);
                a[1][s] = fmaf(g1, kw, a[1][s]);
                a[2][s] = fmaf(g2, kw, a[2][s]);
                a[3][s] = fmaf(g3, kw, a[3][s]);
            }
        }
        #pragma unroll
        for (int i = 0; i < 4; i++) {
            float* yp = y + ybase + (size_t)(j * 4 + i) * (4 * HW_);
            float2 r0; r0.x = a[i][0]; r0.y = a[i][1];
            float2 r1; r1.x = a[i][2]; r1.y = a[i][3];
            *(float2*)yp = r0;
            *(float2*)(yp + 256) = r1;
        }
    }
}

extern "C" void kernel_launch(void* const* d_in, const int* in_sizes, int n_in,
                              void* d_out, int out_size, void* d_ws, size_t ws_size,
                              hipStream_t stream) {
    const float* x  = (const float*)d_in[0];
    const float* wd = (const float*)d_in[1];
    const float* bd = (const float*)d_in[2];
    const float* we = (const float*)d_in[3];
    const float* be = (const float*)d_in[4];
    const float* wo = (const float*)d_in[5];
    const float* bo = (const float*)d_in[6];
    float* y = (float*)d_out;

    unsigned short* t = (unsigned short*)d_ws;             // [NPX][64] bf16 = 8.4 MB
    float* kern = (float*)(t + (size_t)NPX_ * 64);         // [36][NPX] f32  = 9.4 MB
    short* wcomb = (short*)(kern + (size_t)E_ * NPX_);     // [320][256] bf16 = 160 KB
    unsigned short* wBT = (unsigned short*)(wcomb + (size_t)320 * C_);  // [48][576] bf16
    unsigned short* Gq  = wBT + (size_t)48 * 576;          // 33.5 MB

    k_prep<<<188,  256, 0, stream>>>(wo, wd, wcomb, we, wBT);
    k_gemm<<<512,  512, 0, stream>>>(x, wcomb, bd, Gq, t);
    k_enc <<<1024, 256, 0, stream>>>(t, wBT, be, kern);
    k_up  <<<2048, 256, 0, stream>>>(Gq, kern, bo, y);
}